// Round 1
// baseline (2886.521 us; speedup 1.0000x reference)
//
#include <hip/hip_runtime.h>

#define FDIM 128
#define FCLS 40

// ---------------------------------------------------------------------------
// degree: deg[dst[e]] += 1  (atomics; deg buffer pre-zeroed)
// ---------------------------------------------------------------------------
__global__ __launch_bounds__(256) void deg_kernel(const int* __restrict__ dst,
                                                  float* __restrict__ deg, int E) {
    int e = blockIdx.x * 256 + threadIdx.x;
    if (e < E) atomicAdd(&deg[dst[e]], 1.0f);
}

// dinv[i] = rsqrt(deg[i] + 1)   (self-loop included)
__global__ __launch_bounds__(256) void dinv_kernel(float* __restrict__ deg, int N) {
    int i = blockIdx.x * 256 + threadIdx.x;
    if (i < N) deg[i] = rsqrtf(deg[i] + 1.0f);
}

// ---------------------------------------------------------------------------
// C[M,128] = A[M,128] @ W[128,128]
// block = 256 threads, 32 rows/block. A-tile staged in LDS; W read from L2
// (64 KB, shared by all blocks). Each thread owns one column and 16 rows.
// LDS reads are wave-broadcast (same address across the 64 lanes of a wave).
// ---------------------------------------------------------------------------
__global__ __launch_bounds__(256) void gemm128(const float* __restrict__ A,
                                               const float* __restrict__ W,
                                               float* __restrict__ C, int M) {
    __shared__ float As[32][FDIM];
    int row0 = blockIdx.x * 32;
    int nrows = M - row0; if (nrows > 32) nrows = 32;
    {
        const float4* A4 = (const float4*)(A + (size_t)row0 * FDIM);
        float4* S4 = (float4*)As;
        int n4 = nrows * (FDIM / 4);
        for (int i = threadIdx.x; i < n4; i += 256) S4[i] = A4[i];
    }
    __syncthreads();

    int col = threadIdx.x & 127;
    int r0  = threadIdx.x >> 7;          // 0 or 1; rows r0, r0+2, ..., r0+30
    float acc[16];
#pragma unroll
    for (int i = 0; i < 16; ++i) acc[i] = 0.0f;

    for (int k = 0; k < FDIM; k += 4) {
        float w0 = W[(k + 0) * FDIM + col];
        float w1 = W[(k + 1) * FDIM + col];
        float w2 = W[(k + 2) * FDIM + col];
        float w3 = W[(k + 3) * FDIM + col];
#pragma unroll
        for (int i = 0; i < 16; ++i) {
            float4 a = *(const float4*)&As[r0 + 2 * i][k];
            acc[i] = fmaf(a.x, w0, acc[i]);
            acc[i] = fmaf(a.y, w1, acc[i]);
            acc[i] = fmaf(a.z, w2, acc[i]);
            acc[i] = fmaf(a.w, w3, acc[i]);
        }
    }
#pragma unroll
    for (int i = 0; i < 16; ++i) {
        int r = r0 + 2 * i;
        if (r < nrows) C[(size_t)(row0 + r) * FDIM + col] = acc[i];
    }
}

// ---------------------------------------------------------------------------
// AGG[i][f] = H[i][f] * dinv[i]^2 + b[f]   (self-loop term + bias; replaces memset)
// one thread per float4
// ---------------------------------------------------------------------------
__global__ __launch_bounds__(256) void init_self(const float* __restrict__ H,
                                                 const float* __restrict__ dinv,
                                                 const float* __restrict__ b,
                                                 float* __restrict__ AGG, int N) {
    int idx = blockIdx.x * 256 + threadIdx.x;      // over N * 32 float4s
    int total = N * (FDIM / 4);
    if (idx >= total) return;
    int node = idx >> 5;
    int f4 = (idx & 31) << 2;
    float di = dinv[node];
    float d2 = di * di;
    float4 h = ((const float4*)H)[idx];
    float4 o;
    o.x = fmaf(h.x, d2, b[f4 + 0]);
    o.y = fmaf(h.y, d2, b[f4 + 1]);
    o.z = fmaf(h.z, d2, b[f4 + 2]);
    o.w = fmaf(h.w, d2, b[f4 + 3]);
    ((float4*)AGG)[idx] = o;
}

// ---------------------------------------------------------------------------
// AGG[dst[e]] += H[src[e]] * dinv[src]*dinv[dst]    (32 threads per edge, float4 each)
// ---------------------------------------------------------------------------
__global__ __launch_bounds__(256) void edge_agg(const int* __restrict__ src,
                                                const int* __restrict__ dst,
                                                const float* __restrict__ dinv,
                                                const float* __restrict__ H,
                                                float* __restrict__ AGG, int E) {
    int gid = blockIdx.x * 256 + threadIdx.x;      // E*32 threads
    int e = gid >> 5;
    if (e >= E) return;
    int f4 = (gid & 31) << 2;
    int s = src[e];
    int d = dst[e];
    float coef = dinv[s] * dinv[d];
    float4 h = *(const float4*)(H + (size_t)s * FDIM + f4);
    float* p = AGG + (size_t)d * FDIM + f4;
    atomicAdd(p + 0, h.x * coef);
    atomicAdd(p + 1, h.y * coef);
    atomicAdd(p + 2, h.z * coef);
    atomicAdd(p + 3, h.w * coef);
}

// in-place ReLU over N*128 floats (as float4)
__global__ __launch_bounds__(256) void relu_kernel(float* __restrict__ A, int total4) {
    int idx = blockIdx.x * 256 + threadIdx.x;
    if (idx >= total4) return;
    float4 v = ((float4*)A)[idx];
    v.x = fmaxf(v.x, 0.0f);
    v.y = fmaxf(v.y, 0.0f);
    v.z = fmaxf(v.z, 0.0f);
    v.w = fmaxf(v.w, 0.0f);
    ((float4*)A)[idx] = v;
}

// ---------------------------------------------------------------------------
// out[M,40] = H[M,128] @ Wc[128,40] + bc
// ---------------------------------------------------------------------------
__global__ __launch_bounds__(256) void classifier(const float* __restrict__ H,
                                                  const float* __restrict__ Wc,
                                                  const float* __restrict__ bc,
                                                  float* __restrict__ out, int M) {
    __shared__ float Hs[32][FDIM];
    int row0 = blockIdx.x * 32;
    int nrows = M - row0; if (nrows > 32) nrows = 32;
    {
        const float4* A4 = (const float4*)(H + (size_t)row0 * FDIM);
        float4* S4 = (float4*)Hs;
        int n4 = nrows * (FDIM / 4);
        for (int i = threadIdx.x; i < n4; i += 256) S4[i] = A4[i];
    }
    __syncthreads();

    int tot = nrows * FCLS;
    for (int o = threadIdx.x; o < tot; o += 256) {
        int r = o / FCLS;
        int c = o - r * FCLS;
        float acc = bc[c];
        for (int k = 0; k < FDIM; k += 4) {
            float4 a = *(const float4*)&Hs[r][k];
            acc = fmaf(a.x, Wc[(k + 0) * FCLS + c], acc);
            acc = fmaf(a.y, Wc[(k + 1) * FCLS + c], acc);
            acc = fmaf(a.z, Wc[(k + 2) * FCLS + c], acc);
            acc = fmaf(a.w, Wc[(k + 3) * FCLS + c], acc);
        }
        out[(size_t)(row0 + r) * FCLS + c] = acc;
    }
}

// ---------------------------------------------------------------------------
extern "C" void kernel_launch(void* const* d_in, const int* in_sizes, int n_in,
                              void* d_out, int out_size, void* d_ws, size_t ws_size,
                              hipStream_t stream) {
    const float* x  = (const float*)d_in[0];
    const int*   ei = (const int*)d_in[1];
    const float* W1 = (const float*)d_in[2];
    const float* b1 = (const float*)d_in[3];
    const float* W2 = (const float*)d_in[4];
    const float* b2 = (const float*)d_in[5];
    const float* Wc = (const float*)d_in[6];
    const float* bc = (const float*)d_in[7];
    float* out = (float*)d_out;

    int N = in_sizes[0] / FDIM;
    int E = in_sizes[1] / 2;
    const int* src = ei;
    const int* dst = ei + E;

    // workspace layout: dinv[N] | bufA[N*128] | bufB[N*128]  (~51.5 MB total)
    float* dinv = (float*)d_ws;
    float* bufA = dinv + N;
    float* bufB = bufA + (size_t)N * FDIM;

    int vec4 = N * (FDIM / 4);
    int gemmBlocks = (N + 31) / 32;
    int eb = (E * 32 + 255) / 256;
    int vb = (vec4 + 255) / 256;

    // degrees -> dinv
    hipMemsetAsync(dinv, 0, (size_t)N * sizeof(float), stream);
    deg_kernel<<<(E + 255) / 256, 256, 0, stream>>>(dst, dinv, E);
    dinv_kernel<<<(N + 255) / 256, 256, 0, stream>>>(dinv, N);

    // ---- layer 1 ----
    gemm128<<<gemmBlocks, 256, 0, stream>>>(x, W1, bufA, N);
    init_self<<<vb, 256, 0, stream>>>(bufA, dinv, b1, bufB, N);
    edge_agg<<<eb, 256, 0, stream>>>(src, dst, dinv, bufA, bufB, E);
    relu_kernel<<<vb, 256, 0, stream>>>(bufB, vec4);

    // ---- layer 2 ----
    gemm128<<<gemmBlocks, 256, 0, stream>>>(bufB, W2, bufA, N);
    init_self<<<vb, 256, 0, stream>>>(bufA, dinv, b2, bufB, N);
    edge_agg<<<eb, 256, 0, stream>>>(src, dst, dinv, bufA, bufB, E);
    relu_kernel<<<vb, 256, 0, stream>>>(bufB, vec4);

    // ---- classifier ----
    classifier<<<gemmBlocks, 256, 0, stream>>>(bufB, Wc, bc, out, N);
}

// Round 2
// 367.999 us; speedup vs baseline: 7.8438x; 7.8438x over previous
//
#include <hip/hip_runtime.h>

#define FDIM 128
#define FCLS 40

// ---------------------------------------------------------------------------
// int histogram of dst: cnt[dst[e]] += 1
// ---------------------------------------------------------------------------
__global__ __launch_bounds__(256) void deg_kernel(const int* __restrict__ dst,
                                                  int* __restrict__ cnt, int E) {
    int e = blockIdx.x * 256 + threadIdx.x;
    if (e < E) atomicAdd(&cnt[dst[e]], 1);
}

// dinv[i] = rsqrt(cnt[i] + 1)   (self-loop included)
__global__ __launch_bounds__(256) void dinv_kernel(const int* __restrict__ cnt,
                                                   float* __restrict__ dinv, int N) {
    int i = blockIdx.x * 256 + threadIdx.x;
    if (i < N) dinv[i] = rsqrtf((float)cnt[i] + 1.0f);
}

// ---------------------------------------------------------------------------
// exclusive scan of cnt[N] -> offsets[N+1], 1024 elems/block (256 thr x 4)
// ---------------------------------------------------------------------------
__global__ __launch_bounds__(256) void scan_partial(const int* __restrict__ cnt,
                                                    int* __restrict__ blockSums, int N) {
    __shared__ int s[256];
    int t = threadIdx.x;
    int base = blockIdx.x * 1024 + t * 4;
    int v = 0;
#pragma unroll
    for (int j = 0; j < 4; ++j) if (base + j < N) v += cnt[base + j];
    s[t] = v;
    __syncthreads();
    for (int off = 128; off > 0; off >>= 1) {
        if (t < off) s[t] += s[t + off];
        __syncthreads();
    }
    if (t == 0) blockSums[blockIdx.x] = s[0];
}

__global__ __launch_bounds__(256) void scan_block(int* __restrict__ blockSums, int nb) {
    __shared__ int s[256];
    int t = threadIdx.x;
    s[t] = (t < nb) ? blockSums[t] : 0;
    __syncthreads();
    for (int off = 1; off < 256; off <<= 1) {
        int x = 0;
        if (t >= off) x = s[t - off];
        __syncthreads();
        s[t] += x;
        __syncthreads();
    }
    if (t < nb) blockSums[t] = (t > 0) ? s[t - 1] : 0;   // exclusive
}

__global__ __launch_bounds__(256) void scan_final(const int* __restrict__ cnt,
                                                  const int* __restrict__ blockSums,
                                                  int* __restrict__ offsets, int N) {
    __shared__ int s[256];
    int t = threadIdx.x;
    int idx = blockIdx.x * 1024 + t * 4;
    int v[4];
    int sum = 0;
#pragma unroll
    for (int j = 0; j < 4; ++j) {
        v[j] = (idx + j < N) ? cnt[idx + j] : 0;
        sum += v[j];
    }
    s[t] = sum;
    __syncthreads();
    for (int off = 1; off < 256; off <<= 1) {
        int x = 0;
        if (t >= off) x = s[t - off];
        __syncthreads();
        s[t] += x;
        __syncthreads();
    }
    int running = blockSums[blockIdx.x] + s[t] - sum;    // exclusive prefix
#pragma unroll
    for (int j = 0; j < 4; ++j) {
        if (idx + j < N) {
            offsets[idx + j] = running;
            running += v[j];
            if (idx + j == N - 1) offsets[N] = running;
        }
    }
}

// scatter edges into CSR order (by dst); cursor pre-initialized to offsets
__global__ __launch_bounds__(256) void scatter_kernel(const int* __restrict__ src,
                                                      const int* __restrict__ dst,
                                                      int* __restrict__ cursor,
                                                      int* __restrict__ srcAdj, int E) {
    int e = blockIdx.x * 256 + threadIdx.x;
    if (e >= E) return;
    int d = dst[e];
    int pos = atomicAdd(&cursor[d], 1);
    srcAdj[pos] = src[e];
}

// ---------------------------------------------------------------------------
// C[M,128] = A[M,128] @ W[128,128]
// ---------------------------------------------------------------------------
__global__ __launch_bounds__(256) void gemm128(const float* __restrict__ A,
                                               const float* __restrict__ W,
                                               float* __restrict__ C, int M) {
    __shared__ float As[32][FDIM];
    int row0 = blockIdx.x * 32;
    int nrows = M - row0; if (nrows > 32) nrows = 32;
    {
        const float4* A4 = (const float4*)(A + (size_t)row0 * FDIM);
        float4* S4 = (float4*)As;
        int n4 = nrows * (FDIM / 4);
        for (int i = threadIdx.x; i < n4; i += 256) S4[i] = A4[i];
    }
    __syncthreads();

    int col = threadIdx.x & 127;
    int r0  = threadIdx.x >> 7;
    float acc[16];
#pragma unroll
    for (int i = 0; i < 16; ++i) acc[i] = 0.0f;

    for (int k = 0; k < FDIM; k += 4) {
        float w0 = W[(k + 0) * FDIM + col];
        float w1 = W[(k + 1) * FDIM + col];
        float w2 = W[(k + 2) * FDIM + col];
        float w3 = W[(k + 3) * FDIM + col];
#pragma unroll
        for (int i = 0; i < 16; ++i) {
            float4 a = *(const float4*)&As[r0 + 2 * i][k];
            acc[i] = fmaf(a.x, w0, acc[i]);
            acc[i] = fmaf(a.y, w1, acc[i]);
            acc[i] = fmaf(a.z, w2, acc[i]);
            acc[i] = fmaf(a.w, w3, acc[i]);
        }
    }
#pragma unroll
    for (int i = 0; i < 16; ++i) {
        int r = r0 + 2 * i;
        if (r < nrows) C[(size_t)(row0 + r) * FDIM + col] = acc[i];
    }
}

// ---------------------------------------------------------------------------
// Fused aggregation: OUT[d] = relu?( sum_{e in CSR(d)} dinv[src]*dinv[d]*H[src]
//                                    + dinv[d]^2 * H[d] + b )
// one 32-lane half-wave per node (lane = float4 index), 8 nodes per block
// ---------------------------------------------------------------------------
template <bool RELU>
__global__ __launch_bounds__(256) void agg_fused(const float* __restrict__ H,
                                                 const float* __restrict__ dinv,
                                                 const float* __restrict__ bias,
                                                 const int* __restrict__ srcAdj,
                                                 const int* __restrict__ offsets,
                                                 float* __restrict__ OUT, int N) {
    int node = blockIdx.x * 8 + (threadIdx.x >> 5);
    if (node >= N) return;
    int lane = threadIdx.x & 31;

    const float4* H4 = (const float4*)H;
    float di = dinv[node];
    float d2 = di * di;

    float4 h = H4[(size_t)node * 32 + lane];
    float4 acc;
    acc.x = h.x * d2; acc.y = h.y * d2; acc.z = h.z * d2; acc.w = h.w * d2;

    int e   = offsets[node];
    int end = offsets[node + 1];
    for (; e + 2 <= end; e += 2) {
        int s0 = srcAdj[e];
        int s1 = srcAdj[e + 1];
        float c0 = dinv[s0] * di;
        float c1 = dinv[s1] * di;
        float4 a = H4[(size_t)s0 * 32 + lane];
        float4 b = H4[(size_t)s1 * 32 + lane];
        acc.x = fmaf(a.x, c0, acc.x); acc.y = fmaf(a.y, c0, acc.y);
        acc.z = fmaf(a.z, c0, acc.z); acc.w = fmaf(a.w, c0, acc.w);
        acc.x = fmaf(b.x, c1, acc.x); acc.y = fmaf(b.y, c1, acc.y);
        acc.z = fmaf(b.z, c1, acc.z); acc.w = fmaf(b.w, c1, acc.w);
    }
    if (e < end) {
        int s0 = srcAdj[e];
        float c0 = dinv[s0] * di;
        float4 a = H4[(size_t)s0 * 32 + lane];
        acc.x = fmaf(a.x, c0, acc.x); acc.y = fmaf(a.y, c0, acc.y);
        acc.z = fmaf(a.z, c0, acc.z); acc.w = fmaf(a.w, c0, acc.w);
    }

    float4 bb = ((const float4*)bias)[lane];
    acc.x += bb.x; acc.y += bb.y; acc.z += bb.z; acc.w += bb.w;
    if (RELU) {
        acc.x = fmaxf(acc.x, 0.0f); acc.y = fmaxf(acc.y, 0.0f);
        acc.z = fmaxf(acc.z, 0.0f); acc.w = fmaxf(acc.w, 0.0f);
    }
    ((float4*)OUT)[(size_t)node * 32 + lane] = acc;
}

// ---------------------------------------------------------------------------
// out[M,40] = H[M,128] @ Wc[128,40] + bc
// ---------------------------------------------------------------------------
__global__ __launch_bounds__(256) void classifier(const float* __restrict__ H,
                                                  const float* __restrict__ Wc,
                                                  const float* __restrict__ bc,
                                                  float* __restrict__ out, int M) {
    __shared__ float Hs[32][FDIM];
    int row0 = blockIdx.x * 32;
    int nrows = M - row0; if (nrows > 32) nrows = 32;
    {
        const float4* A4 = (const float4*)(H + (size_t)row0 * FDIM);
        float4* S4 = (float4*)Hs;
        int n4 = nrows * (FDIM / 4);
        for (int i = threadIdx.x; i < n4; i += 256) S4[i] = A4[i];
    }
    __syncthreads();

    int tot = nrows * FCLS;
    for (int o = threadIdx.x; o < tot; o += 256) {
        int r = o / FCLS;
        int c = o - r * FCLS;
        float acc = bc[c];
        for (int k = 0; k < FDIM; k += 4) {
            float4 a = *(const float4*)&Hs[r][k];
            acc = fmaf(a.x, Wc[(k + 0) * FCLS + c], acc);
            acc = fmaf(a.y, Wc[(k + 1) * FCLS + c], acc);
            acc = fmaf(a.z, Wc[(k + 2) * FCLS + c], acc);
            acc = fmaf(a.w, Wc[(k + 3) * FCLS + c], acc);
        }
        out[(size_t)(row0 + r) * FCLS + c] = acc;
    }
}

// ---------------------------------------------------------------------------
extern "C" void kernel_launch(void* const* d_in, const int* in_sizes, int n_in,
                              void* d_out, int out_size, void* d_ws, size_t ws_size,
                              hipStream_t stream) {
    const float* x  = (const float*)d_in[0];
    const int*   ei = (const int*)d_in[1];
    const float* W1 = (const float*)d_in[2];
    const float* b1 = (const float*)d_in[3];
    const float* W2 = (const float*)d_in[4];
    const float* b2 = (const float*)d_in[5];
    const float* Wc = (const float*)d_in[6];
    const float* bc = (const float*)d_in[7];
    float* out = (float*)d_out;

    int N = in_sizes[0] / FDIM;
    int E = in_sizes[1] / 2;
    const int* src = ei;
    const int* dst = ei + E;

    // workspace layout (floats/ints, 4B):
    // dinv[N] | bufA[N*128] | bufB[N*128] | cnt[N] | offsets[N+1] | cursor[N]
    // | srcAdj[E] | blockSums[256]
    float* dinv    = (float*)d_ws;
    float* bufA    = dinv + N;
    float* bufB    = bufA + (size_t)N * FDIM;
    int*   cnt     = (int*)(bufB + (size_t)N * FDIM);
    int*   offsets = cnt + N;
    int*   cursor  = offsets + (N + 1);
    int*   srcAdj  = cursor + N;
    int*   blockSums = srcAdj + E;

    int gemmBlocks = (N + 31) / 32;
    int aggBlocks  = (N + 7) / 8;
    int nScan = (N + 1023) / 1024;           // 49 blocks (<=256)

    // ---- CSR build ----
    hipMemsetAsync(cnt, 0, (size_t)N * sizeof(int), stream);
    deg_kernel<<<(E + 255) / 256, 256, 0, stream>>>(dst, cnt, E);
    dinv_kernel<<<(N + 255) / 256, 256, 0, stream>>>(cnt, dinv, N);
    scan_partial<<<nScan, 256, 0, stream>>>(cnt, blockSums, N);
    scan_block<<<1, 256, 0, stream>>>(blockSums, nScan);
    scan_final<<<nScan, 256, 0, stream>>>(cnt, blockSums, offsets, N);
    hipMemcpyAsync(cursor, offsets, (size_t)N * sizeof(int),
                   hipMemcpyDeviceToDevice, stream);
    scatter_kernel<<<(E + 255) / 256, 256, 0, stream>>>(src, dst, cursor, srcAdj, E);

    // ---- layer 1 ----
    gemm128<<<gemmBlocks, 256, 0, stream>>>(x, W1, bufA, N);
    agg_fused<true><<<aggBlocks, 256, 0, stream>>>(bufA, dinv, b1, srcAdj, offsets, bufB, N);

    // ---- layer 2 ----
    gemm128<<<gemmBlocks, 256, 0, stream>>>(bufB, W2, bufA, N);
    agg_fused<true><<<aggBlocks, 256, 0, stream>>>(bufA, dinv, b2, srcAdj, offsets, bufB, N);

    // ---- classifier ----
    classifier<<<gemmBlocks, 256, 0, stream>>>(bufB, Wc, bc, out, N);
}

// Round 3
// 305.096 us; speedup vs baseline: 9.4610x; 1.2062x over previous
//
#include <hip/hip_runtime.h>

#define FDIM 128
#define FCLS 40

// ---- bf16 helpers (bit-level, RNE) ----------------------------------------
__device__ __forceinline__ float bf2f(unsigned short u) {
    union { unsigned int i; float f; } v; v.i = ((unsigned int)u) << 16; return v.f;
}
__device__ __forceinline__ unsigned short f2bf(float f) {
    union { float f; unsigned int i; } v; v.f = f;
    unsigned int u = v.i + 0x7FFFu + ((v.i >> 16) & 1u);   // round-nearest-even
    return (unsigned short)(u >> 16);
}

// ---------------------------------------------------------------------------
// int histogram of dst: cnt[dst[e]] += 1
// ---------------------------------------------------------------------------
__global__ __launch_bounds__(256) void deg_kernel(const int* __restrict__ dst,
                                                  int* __restrict__ cnt, int E) {
    int e = blockIdx.x * 256 + threadIdx.x;
    if (e < E) atomicAdd(&cnt[dst[e]], 1);
}

// ---------------------------------------------------------------------------
// exclusive scan of cnt[N] -> offsets[N+1] (+ cursor copy + dinv), 1024/block
// ---------------------------------------------------------------------------
__global__ __launch_bounds__(256) void scan_partial(const int* __restrict__ cnt,
                                                    int* __restrict__ blockSums, int N) {
    __shared__ int s[256];
    int t = threadIdx.x;
    int base = blockIdx.x * 1024 + t * 4;
    int v = 0;
#pragma unroll
    for (int j = 0; j < 4; ++j) if (base + j < N) v += cnt[base + j];
    s[t] = v;
    __syncthreads();
    for (int off = 128; off > 0; off >>= 1) {
        if (t < off) s[t] += s[t + off];
        __syncthreads();
    }
    if (t == 0) blockSums[blockIdx.x] = s[0];
}

__global__ __launch_bounds__(256) void scan_block(int* __restrict__ blockSums, int nb) {
    __shared__ int s[256];
    int t = threadIdx.x;
    s[t] = (t < nb) ? blockSums[t] : 0;
    __syncthreads();
    for (int off = 1; off < 256; off <<= 1) {
        int x = 0;
        if (t >= off) x = s[t - off];
        __syncthreads();
        s[t] += x;
        __syncthreads();
    }
    if (t < nb) blockSums[t] = (t > 0) ? s[t - 1] : 0;   // exclusive
}

__global__ __launch_bounds__(256) void scan_final(const int* __restrict__ cnt,
                                                  const int* __restrict__ blockSums,
                                                  int* __restrict__ offsets,
                                                  int* __restrict__ cursor,
                                                  float* __restrict__ dinv, int N) {
    __shared__ int s[256];
    int t = threadIdx.x;
    int idx = blockIdx.x * 1024 + t * 4;
    int v[4];
    int sum = 0;
#pragma unroll
    for (int j = 0; j < 4; ++j) {
        v[j] = (idx + j < N) ? cnt[idx + j] : 0;
        sum += v[j];
    }
    s[t] = sum;
    __syncthreads();
    for (int off = 1; off < 256; off <<= 1) {
        int x = 0;
        if (t >= off) x = s[t - off];
        __syncthreads();
        s[t] += x;
        __syncthreads();
    }
    int running = blockSums[blockIdx.x] + s[t] - sum;    // exclusive prefix
#pragma unroll
    for (int j = 0; j < 4; ++j) {
        if (idx + j < N) {
            offsets[idx + j] = running;
            cursor[idx + j]  = running;
            dinv[idx + j]    = rsqrtf((float)v[j] + 1.0f);
            running += v[j];
            if (idx + j == N - 1) offsets[N] = running;
        }
    }
}

// scatter edges into CSR order (by dst); cursor pre-initialized to offsets
__global__ __launch_bounds__(256) void scatter_kernel(const int* __restrict__ src,
                                                      const int* __restrict__ dst,
                                                      int* __restrict__ cursor,
                                                      int* __restrict__ srcAdj, int E) {
    int e = blockIdx.x * 256 + threadIdx.x;
    if (e >= E) return;
    int d = dst[e];
    int pos = atomicAdd(&cursor[d], 1);
    srcAdj[pos] = src[e];
}

// ---------------------------------------------------------------------------
// C[M,128](bf16) = A[M,128](f32) @ W[128,128](f32)
// ---------------------------------------------------------------------------
__global__ __launch_bounds__(256) void gemm128(const float* __restrict__ A,
                                               const float* __restrict__ W,
                                               unsigned short* __restrict__ C, int M) {
    __shared__ float As[32][FDIM];
    int row0 = blockIdx.x * 32;
    int nrows = M - row0; if (nrows > 32) nrows = 32;
    {
        const float4* A4 = (const float4*)(A + (size_t)row0 * FDIM);
        float4* S4 = (float4*)As;
        int n4 = nrows * (FDIM / 4);
        for (int i = threadIdx.x; i < n4; i += 256) S4[i] = A4[i];
    }
    __syncthreads();

    int col = threadIdx.x & 127;
    int r0  = threadIdx.x >> 7;
    float acc[16];
#pragma unroll
    for (int i = 0; i < 16; ++i) acc[i] = 0.0f;

    for (int k = 0; k < FDIM; k += 4) {
        float w0 = W[(k + 0) * FDIM + col];
        float w1 = W[(k + 1) * FDIM + col];
        float w2 = W[(k + 2) * FDIM + col];
        float w3 = W[(k + 3) * FDIM + col];
#pragma unroll
        for (int i = 0; i < 16; ++i) {
            float4 a = *(const float4*)&As[r0 + 2 * i][k];
            acc[i] = fmaf(a.x, w0, acc[i]);
            acc[i] = fmaf(a.y, w1, acc[i]);
            acc[i] = fmaf(a.z, w2, acc[i]);
            acc[i] = fmaf(a.w, w3, acc[i]);
        }
    }
#pragma unroll
    for (int i = 0; i < 16; ++i) {
        int r = r0 + 2 * i;
        if (r < nrows) C[(size_t)(row0 + r) * FDIM + col] = f2bf(acc[i]);
    }
}

// ---------------------------------------------------------------------------
// Fused aggregation (bf16 gather -> f32 out):
// OUT[d] = relu?( sum_{e in CSR(d)} dinv[src]*dinv[d]*H[src] + dinv[d]^2*H[d] + b )
// one 32-lane half-wave per node (lane = 4-elem chunk), 8 nodes per block
// ---------------------------------------------------------------------------
template <bool RELU>
__global__ __launch_bounds__(256) void agg_fused(const unsigned short* __restrict__ H,
                                                 const float* __restrict__ dinv,
                                                 const float* __restrict__ bias,
                                                 const int* __restrict__ srcAdj,
                                                 const int* __restrict__ offsets,
                                                 float* __restrict__ OUT, int N) {
    int node = blockIdx.x * 8 + (threadIdx.x >> 5);
    if (node >= N) return;
    int lane = threadIdx.x & 31;

    const ushort4* H4 = (const ushort4*)H;         // row stride = 32 ushort4
    float di = dinv[node];
    float d2 = di * di;

    ushort4 h = H4[(size_t)node * 32 + lane];
    float4 acc;
    acc.x = bf2f(h.x) * d2; acc.y = bf2f(h.y) * d2;
    acc.z = bf2f(h.z) * d2; acc.w = bf2f(h.w) * d2;

    int e   = offsets[node];
    int end = offsets[node + 1];
    for (; e + 4 <= end; e += 4) {
        int s0 = srcAdj[e + 0], s1 = srcAdj[e + 1];
        int s2 = srcAdj[e + 2], s3 = srcAdj[e + 3];
        float c0 = dinv[s0] * di, c1 = dinv[s1] * di;
        float c2 = dinv[s2] * di, c3 = dinv[s3] * di;
        ushort4 a0 = H4[(size_t)s0 * 32 + lane];
        ushort4 a1 = H4[(size_t)s1 * 32 + lane];
        ushort4 a2 = H4[(size_t)s2 * 32 + lane];
        ushort4 a3 = H4[(size_t)s3 * 32 + lane];
        acc.x = fmaf(bf2f(a0.x), c0, acc.x); acc.y = fmaf(bf2f(a0.y), c0, acc.y);
        acc.z = fmaf(bf2f(a0.z), c0, acc.z); acc.w = fmaf(bf2f(a0.w), c0, acc.w);
        acc.x = fmaf(bf2f(a1.x), c1, acc.x); acc.y = fmaf(bf2f(a1.y), c1, acc.y);
        acc.z = fmaf(bf2f(a1.z), c1, acc.z); acc.w = fmaf(bf2f(a1.w), c1, acc.w);
        acc.x = fmaf(bf2f(a2.x), c2, acc.x); acc.y = fmaf(bf2f(a2.y), c2, acc.y);
        acc.z = fmaf(bf2f(a2.z), c2, acc.z); acc.w = fmaf(bf2f(a2.w), c2, acc.w);
        acc.x = fmaf(bf2f(a3.x), c3, acc.x); acc.y = fmaf(bf2f(a3.y), c3, acc.y);
        acc.z = fmaf(bf2f(a3.z), c3, acc.z); acc.w = fmaf(bf2f(a3.w), c3, acc.w);
    }
    for (; e < end; ++e) {
        int s0 = srcAdj[e];
        float c0 = dinv[s0] * di;
        ushort4 a0 = H4[(size_t)s0 * 32 + lane];
        acc.x = fmaf(bf2f(a0.x), c0, acc.x); acc.y = fmaf(bf2f(a0.y), c0, acc.y);
        acc.z = fmaf(bf2f(a0.z), c0, acc.z); acc.w = fmaf(bf2f(a0.w), c0, acc.w);
    }

    float4 bb = ((const float4*)bias)[lane];
    acc.x += bb.x; acc.y += bb.y; acc.z += bb.z; acc.w += bb.w;
    if (RELU) {
        acc.x = fmaxf(acc.x, 0.0f); acc.y = fmaxf(acc.y, 0.0f);
        acc.z = fmaxf(acc.z, 0.0f); acc.w = fmaxf(acc.w, 0.0f);
    }
    ((float4*)OUT)[(size_t)node * 32 + lane] = acc;
}

// ---------------------------------------------------------------------------
// out[M,40] = H[M,128] @ Wc[128,40] + bc   (all f32)
// ---------------------------------------------------------------------------
__global__ __launch_bounds__(256) void classifier(const float* __restrict__ H,
                                                  const float* __restrict__ Wc,
                                                  const float* __restrict__ bc,
                                                  float* __restrict__ out, int M) {
    __shared__ float Hs[32][FDIM];
    int row0 = blockIdx.x * 32;
    int nrows = M - row0; if (nrows > 32) nrows = 32;
    {
        const float4* A4 = (const float4*)(H + (size_t)row0 * FDIM);
        float4* S4 = (float4*)Hs;
        int n4 = nrows * (FDIM / 4);
        for (int i = threadIdx.x; i < n4; i += 256) S4[i] = A4[i];
    }
    __syncthreads();

    int tot = nrows * FCLS;
    for (int o = threadIdx.x; o < tot; o += 256) {
        int r = o / FCLS;
        int c = o - r * FCLS;
        float acc = bc[c];
        for (int k = 0; k < FDIM; k += 4) {
            float4 a = *(const float4*)&Hs[r][k];
            acc = fmaf(a.x, Wc[(k + 0) * FCLS + c], acc);
            acc = fmaf(a.y, Wc[(k + 1) * FCLS + c], acc);
            acc = fmaf(a.z, Wc[(k + 2) * FCLS + c], acc);
            acc = fmaf(a.w, Wc[(k + 3) * FCLS + c], acc);
        }
        out[(size_t)(row0 + r) * FCLS + c] = acc;
    }
}

// ---------------------------------------------------------------------------
extern "C" void kernel_launch(void* const* d_in, const int* in_sizes, int n_in,
                              void* d_out, int out_size, void* d_ws, size_t ws_size,
                              hipStream_t stream) {
    const float* x  = (const float*)d_in[0];
    const int*   ei = (const int*)d_in[1];
    const float* W1 = (const float*)d_in[2];
    const float* b1 = (const float*)d_in[3];
    const float* W2 = (const float*)d_in[4];
    const float* b2 = (const float*)d_in[5];
    const float* Wc = (const float*)d_in[6];
    const float* bc = (const float*)d_in[7];
    float* out = (float*)d_out;

    int N = in_sizes[0] / FDIM;
    int E = in_sizes[1] / 2;
    const int* src = ei;
    const int* dst = ei + E;

    // workspace layout (4B units):
    // dinv[N] | A f32[N*128] | H bf16[N*128 ushort = N*64 words] | cnt[N]
    // | offsets[N+1] | cursor[N] | srcAdj[E] | blockSums[256]
    float*          dinv   = (float*)d_ws;
    float*          bufA   = dinv + N;                       // f32 [N*128]
    unsigned short* bufH   = (unsigned short*)(bufA + (size_t)N * FDIM);
    int*            cnt    = (int*)(bufH + (size_t)N * FDIM);
    int*            offsets = cnt + N;
    int*            cursor  = offsets + (N + 1);
    int*            srcAdj  = cursor + N;
    int*            blockSums = srcAdj + E;

    int gemmBlocks = (N + 31) / 32;
    int aggBlocks  = (N + 7) / 8;
    int nScan = (N + 1023) / 1024;

    // ---- CSR build ----
    hipMemsetAsync(cnt, 0, (size_t)N * sizeof(int), stream);
    deg_kernel<<<(E + 255) / 256, 256, 0, stream>>>(dst, cnt, E);
    scan_partial<<<nScan, 256, 0, stream>>>(cnt, blockSums, N);
    scan_block<<<1, 256, 0, stream>>>(blockSums, nScan);
    scan_final<<<nScan, 256, 0, stream>>>(cnt, blockSums, offsets, cursor, dinv, N);
    scatter_kernel<<<(E + 255) / 256, 256, 0, stream>>>(src, dst, cursor, srcAdj, E);

    // ---- layer 1 ----
    gemm128<<<gemmBlocks, 256, 0, stream>>>(x, W1, bufH, N);
    agg_fused<true><<<aggBlocks, 256, 0, stream>>>(bufH, dinv, b1, srcAdj, offsets, bufA, N);

    // ---- layer 2 ----
    gemm128<<<gemmBlocks, 256, 0, stream>>>(bufA, W2, bufH, N);
    agg_fused<true><<<aggBlocks, 256, 0, stream>>>(bufH, dinv, b2, srcAdj, offsets, bufA, N);

    // ---- classifier ----
    classifier<<<gemmBlocks, 256, 0, stream>>>(bufA, Wc, bc, out, N);
}

// Round 4
// 223.988 us; speedup vs baseline: 12.8869x; 1.3621x over previous
//
#include <hip/hip_runtime.h>

#define FDIM 128
#define FCLS 40

typedef short s16x8 __attribute__((ext_vector_type(8)));   // 8 bf16 (4 VGPRs)
typedef float f32x4 __attribute__((ext_vector_type(4)));   // MFMA accumulator

// ---- bf16 helpers (bit-level, RNE) ----------------------------------------
__device__ __forceinline__ float bf2f(unsigned short u) {
    union { unsigned int i; float f; } v; v.i = ((unsigned int)u) << 16; return v.f;
}
__device__ __forceinline__ unsigned short f2bf(float f) {
    union { float f; unsigned int i; } v; v.f = f;
    unsigned int u = v.i + 0x7FFFu + ((v.i >> 16) & 1u);   // round-nearest-even
    return (unsigned short)(u >> 16);
}

// ---------------------------------------------------------------------------
// CSR build: histogram, scan, scatter
// ---------------------------------------------------------------------------
__global__ __launch_bounds__(256) void deg_kernel(const int* __restrict__ dst,
                                                  int* __restrict__ cnt, int E) {
    int e = blockIdx.x * 256 + threadIdx.x;
    if (e < E) atomicAdd(&cnt[dst[e]], 1);
}

__global__ __launch_bounds__(256) void scan_partial(const int* __restrict__ cnt,
                                                    int* __restrict__ blockSums, int N) {
    __shared__ int s[256];
    int t = threadIdx.x;
    int base = blockIdx.x * 1024 + t * 4;
    int v = 0;
#pragma unroll
    for (int j = 0; j < 4; ++j) if (base + j < N) v += cnt[base + j];
    s[t] = v;
    __syncthreads();
    for (int off = 128; off > 0; off >>= 1) {
        if (t < off) s[t] += s[t + off];
        __syncthreads();
    }
    if (t == 0) blockSums[blockIdx.x] = s[0];
}

__global__ __launch_bounds__(256) void scan_block(int* __restrict__ blockSums, int nb) {
    __shared__ int s[256];
    int t = threadIdx.x;
    s[t] = (t < nb) ? blockSums[t] : 0;
    __syncthreads();
    for (int off = 1; off < 256; off <<= 1) {
        int x = 0;
        if (t >= off) x = s[t - off];
        __syncthreads();
        s[t] += x;
        __syncthreads();
    }
    if (t < nb) blockSums[t] = (t > 0) ? s[t - 1] : 0;   // exclusive
}

__global__ __launch_bounds__(256) void scan_final(const int* __restrict__ cnt,
                                                  const int* __restrict__ blockSums,
                                                  int* __restrict__ offsets,
                                                  int* __restrict__ cursor,
                                                  float* __restrict__ dinv, int N) {
    __shared__ int s[256];
    int t = threadIdx.x;
    int idx = blockIdx.x * 1024 + t * 4;
    int v[4];
    int sum = 0;
#pragma unroll
    for (int j = 0; j < 4; ++j) {
        v[j] = (idx + j < N) ? cnt[idx + j] : 0;
        sum += v[j];
    }
    s[t] = sum;
    __syncthreads();
    for (int off = 1; off < 256; off <<= 1) {
        int x = 0;
        if (t >= off) x = s[t - off];
        __syncthreads();
        s[t] += x;
        __syncthreads();
    }
    int running = blockSums[blockIdx.x] + s[t] - sum;    // exclusive prefix
#pragma unroll
    for (int j = 0; j < 4; ++j) {
        if (idx + j < N) {
            offsets[idx + j] = running;
            cursor[idx + j]  = running;
            dinv[idx + j]    = rsqrtf((float)v[j] + 1.0f);
            running += v[j];
            if (idx + j == N - 1) offsets[N] = running;
        }
    }
}

__global__ __launch_bounds__(256) void scatter_kernel(const int* __restrict__ src,
                                                      const int* __restrict__ dst,
                                                      int* __restrict__ cursor,
                                                      int* __restrict__ srcAdj, int E) {
    int e = blockIdx.x * 256 + threadIdx.x;
    if (e >= E) return;
    int d = dst[e];
    int pos = atomicAdd(&cursor[d], 1);
    srcAdj[pos] = src[e];
}

// ---------------------------------------------------------------------------
// prep: f32 -> bf16 cast (8 elems/thread)
// ---------------------------------------------------------------------------
__global__ __launch_bounds__(256) void cast_bf16(const float* __restrict__ in,
                                                 unsigned short* __restrict__ out, int n8) {
    int i = blockIdx.x * 256 + threadIdx.x;
    if (i >= n8) return;
    const float4* p = (const float4*)in + (size_t)i * 2;
    float4 a = p[0], b = p[1];
    ushort4* o = (ushort4*)out + (size_t)i * 2;
    o[0] = ushort4{f2bf(a.x), f2bf(a.y), f2bf(a.z), f2bf(a.w)};
    o[1] = ushort4{f2bf(b.x), f2bf(b.y), f2bf(b.z), f2bf(b.w)};
}

// ---------------------------------------------------------------------------
// prep: pack W [128][ncols] f32 into MFMA B-fragment order, bf16.
// Wp[((ct*4+ks)*64 + lane)*8 + j] = W[(ks*32 + (lane>>4)*8 + j)][ct*16 + (lane&15)]
// (zero-padded for cols >= ncols). grid = nct blocks of 256.
// ---------------------------------------------------------------------------
__global__ __launch_bounds__(256) void pack_w(const float* __restrict__ W,
                                              unsigned short* __restrict__ Wp,
                                              int ncols, int nct) {
    int t = blockIdx.x * 256 + threadIdx.x;
    if (t >= nct * 256) return;
    int lane = t & 63, ks = (t >> 6) & 3, ct = t >> 8;
    int n  = ct * 16 + (lane & 15);
    int kb = ks * 32 + (lane >> 4) * 8;
    unsigned short v[8];
#pragma unroll
    for (int j = 0; j < 8; ++j) {
        v[j] = (n < ncols) ? f2bf(W[(size_t)(kb + j) * ncols + n]) : (unsigned short)0;
    }
    ushort4* o = (ushort4*)(Wp + (size_t)t * 8);
    o[0] = ushort4{v[0], v[1], v[2], v[3]};
    o[1] = ushort4{v[4], v[5], v[6], v[7]};
}

// ---------------------------------------------------------------------------
// C[M,128](bf16) = A[M,128](bf16) @ W(packed bf16)
// 1 wave = one 16-row tile; 4 waves/block; no LDS, no barriers.
// A frag: row = lane&15, k = (lane>>4)*8 + j  (contiguous 16B/lane)
// C/D:    col = lane&15, row = (lane>>4)*4 + reg   [m89/m91 verified]
// ---------------------------------------------------------------------------
__global__ __launch_bounds__(256) void gemm_mfma(const unsigned short* __restrict__ A,
                                                 const unsigned short* __restrict__ Wp,
                                                 unsigned short* __restrict__ C, int M) {
    int wave = threadIdx.x >> 6;
    int lane = threadIdx.x & 63;
    int row0 = (blockIdx.x * 4 + wave) * 16;
    if (row0 >= M) return;
    int m = lane & 15;          // A-row within tile / C-col within tile
    int g = lane >> 4;          // k-group / C-row-group

    const s16x8* Arow = (const s16x8*)(A + (size_t)(row0 + m) * FDIM);
    s16x8 a[4];
#pragma unroll
    for (int ks = 0; ks < 4; ++ks) a[ks] = Arow[ks * 4 + g];

    for (int ct = 0; ct < 8; ++ct) {
        f32x4 acc = {0.f, 0.f, 0.f, 0.f};
#pragma unroll
        for (int ks = 0; ks < 4; ++ks) {
            s16x8 b = *(const s16x8*)(Wp + ((size_t)((ct * 4 + ks) * 64 + lane)) * 8);
            acc = __builtin_amdgcn_mfma_f32_16x16x32_bf16(a[ks], b, acc, 0, 0, 0);
        }
        int n  = ct * 16 + m;
        int r0 = row0 + g * 4;
#pragma unroll
        for (int r = 0; r < 4; ++r)
            C[(size_t)(r0 + r) * FDIM + n] = f2bf(acc[r]);
    }
}

// ---------------------------------------------------------------------------
// out[M,40](f32) = A[M,128](bf16) @ Wc(packed, 3 col-tiles, zero-padded) + bc
// ---------------------------------------------------------------------------
__global__ __launch_bounds__(256) void classifier_mfma(const unsigned short* __restrict__ A,
                                                       const unsigned short* __restrict__ Wp,
                                                       const float* __restrict__ bc,
                                                       float* __restrict__ out, int M) {
    int wave = threadIdx.x >> 6;
    int lane = threadIdx.x & 63;
    int row0 = (blockIdx.x * 4 + wave) * 16;
    if (row0 >= M) return;
    int m = lane & 15;
    int g = lane >> 4;

    const s16x8* Arow = (const s16x8*)(A + (size_t)(row0 + m) * FDIM);
    s16x8 a[4];
#pragma unroll
    for (int ks = 0; ks < 4; ++ks) a[ks] = Arow[ks * 4 + g];

    for (int ct = 0; ct < 3; ++ct) {
        f32x4 acc = {0.f, 0.f, 0.f, 0.f};
#pragma unroll
        for (int ks = 0; ks < 4; ++ks) {
            s16x8 b = *(const s16x8*)(Wp + ((size_t)((ct * 4 + ks) * 64 + lane)) * 8);
            acc = __builtin_amdgcn_mfma_f32_16x16x32_bf16(a[ks], b, acc, 0, 0, 0);
        }
        int n = ct * 16 + m;
        if (n < FCLS) {
            float bias = bc[n];
            int r0 = row0 + g * 4;
#pragma unroll
            for (int r = 0; r < 4; ++r)
                out[(size_t)(r0 + r) * FCLS + n] = acc[r] + bias;
        }
    }
}

// ---------------------------------------------------------------------------
// Fused aggregation (bf16 gather -> bf16 out):
// OUT[d] = relu( sum_{e in CSR(d)} dinv[src]*dinv[d]*H[src] + dinv[d]^2*H[d] + b )
// one 32-lane half-wave per node (lane = 4-elem chunk), f32 accumulation
// ---------------------------------------------------------------------------
__global__ __launch_bounds__(256) void agg_fused(const unsigned short* __restrict__ H,
                                                 const float* __restrict__ dinv,
                                                 const float* __restrict__ bias,
                                                 const int* __restrict__ srcAdj,
                                                 const int* __restrict__ offsets,
                                                 unsigned short* __restrict__ OUT, int N) {
    int node = blockIdx.x * 8 + (threadIdx.x >> 5);
    if (node >= N) return;
    int lane = threadIdx.x & 31;

    const ushort4* H4 = (const ushort4*)H;         // row stride = 32 ushort4
    float di = dinv[node];
    float d2 = di * di;

    ushort4 h = H4[(size_t)node * 32 + lane];
    float4 acc;
    acc.x = bf2f(h.x) * d2; acc.y = bf2f(h.y) * d2;
    acc.z = bf2f(h.z) * d2; acc.w = bf2f(h.w) * d2;

    int e   = offsets[node];
    int end = offsets[node + 1];
    for (; e + 4 <= end; e += 4) {
        int s0 = srcAdj[e + 0], s1 = srcAdj[e + 1];
        int s2 = srcAdj[e + 2], s3 = srcAdj[e + 3];
        float c0 = dinv[s0] * di, c1 = dinv[s1] * di;
        float c2 = dinv[s2] * di, c3 = dinv[s3] * di;
        ushort4 a0 = H4[(size_t)s0 * 32 + lane];
        ushort4 a1 = H4[(size_t)s1 * 32 + lane];
        ushort4 a2 = H4[(size_t)s2 * 32 + lane];
        ushort4 a3 = H4[(size_t)s3 * 32 + lane];
        acc.x = fmaf(bf2f(a0.x), c0, acc.x); acc.y = fmaf(bf2f(a0.y), c0, acc.y);
        acc.z = fmaf(bf2f(a0.z), c0, acc.z); acc.w = fmaf(bf2f(a0.w), c0, acc.w);
        acc.x = fmaf(bf2f(a1.x), c1, acc.x); acc.y = fmaf(bf2f(a1.y), c1, acc.y);
        acc.z = fmaf(bf2f(a1.z), c1, acc.z); acc.w = fmaf(bf2f(a1.w), c1, acc.w);
        acc.x = fmaf(bf2f(a2.x), c2, acc.x); acc.y = fmaf(bf2f(a2.y), c2, acc.y);
        acc.z = fmaf(bf2f(a2.z), c2, acc.z); acc.w = fmaf(bf2f(a2.w), c2, acc.w);
        acc.x = fmaf(bf2f(a3.x), c3, acc.x); acc.y = fmaf(bf2f(a3.y), c3, acc.y);
        acc.z = fmaf(bf2f(a3.z), c3, acc.z); acc.w = fmaf(bf2f(a3.w), c3, acc.w);
    }
    for (; e < end; ++e) {
        int s0 = srcAdj[e];
        float c0 = dinv[s0] * di;
        ushort4 a0 = H4[(size_t)s0 * 32 + lane];
        acc.x = fmaf(bf2f(a0.x), c0, acc.x); acc.y = fmaf(bf2f(a0.y), c0, acc.y);
        acc.z = fmaf(bf2f(a0.z), c0, acc.z); acc.w = fmaf(bf2f(a0.w), c0, acc.w);
    }

    float4 bb = ((const float4*)bias)[lane];
    acc.x = fmaxf(acc.x + bb.x, 0.0f);
    acc.y = fmaxf(acc.y + bb.y, 0.0f);
    acc.z = fmaxf(acc.z + bb.z, 0.0f);
    acc.w = fmaxf(acc.w + bb.w, 0.0f);
    ((ushort4*)OUT)[(size_t)node * 32 + lane] =
        ushort4{f2bf(acc.x), f2bf(acc.y), f2bf(acc.z), f2bf(acc.w)};
}

// ---------------------------------------------------------------------------
extern "C" void kernel_launch(void* const* d_in, const int* in_sizes, int n_in,
                              void* d_out, int out_size, void* d_ws, size_t ws_size,
                              hipStream_t stream) {
    const float* x  = (const float*)d_in[0];
    const int*   ei = (const int*)d_in[1];
    const float* W1 = (const float*)d_in[2];
    const float* b1 = (const float*)d_in[3];
    const float* W2 = (const float*)d_in[4];
    const float* b2 = (const float*)d_in[5];
    const float* Wc = (const float*)d_in[6];
    const float* bc = (const float*)d_in[7];
    float* out = (float*)d_out;

    int N = in_sizes[0] / FDIM;
    int E = in_sizes[1] / 2;
    const int* src = ei;
    const int* dst = ei + E;

    // workspace layout (2B units for bf16 buffers, 4B for the rest):
    // xb[N*128 bf16] | Hbuf[N*128 bf16] | Abuf[N*128 bf16]
    // | Wp1[8192 us] | Wp2[8192 us] | Wpc[6144 us]
    // | dinv[N f32] | cnt[N] | offsets[N+1] | cursor[N] | srcAdj[E] | blockSums[256]
    unsigned short* xb   = (unsigned short*)d_ws;
    unsigned short* Hbuf = xb   + (size_t)N * FDIM;
    unsigned short* Abuf = Hbuf + (size_t)N * FDIM;
    unsigned short* Wp1  = Abuf + (size_t)N * FDIM;
    unsigned short* Wp2  = Wp1 + 8 * 4 * 64 * 8;
    unsigned short* Wpc  = Wp2 + 8 * 4 * 64 * 8;
    float* dinv    = (float*)(Wpc + 3 * 4 * 64 * 8);
    int*   cnt     = (int*)(dinv + N);
    int*   offsets = cnt + N;
    int*   cursor  = offsets + (N + 1);
    int*   srcAdj  = cursor + N;
    int*   blockSums = srcAdj + E;

    int mfmaBlocks = (N / 16 + 3) / 4;        // 16-row tiles, 4 waves/block
    int aggBlocks  = (N + 7) / 8;
    int nScan = (N + 1023) / 1024;
    int n8 = N * FDIM / 8;

    // ---- CSR build ----
    hipMemsetAsync(cnt, 0, (size_t)N * sizeof(int), stream);
    deg_kernel<<<(E + 255) / 256, 256, 0, stream>>>(dst, cnt, E);
    scan_partial<<<nScan, 256, 0, stream>>>(cnt, blockSums, N);
    scan_block<<<1, 256, 0, stream>>>(blockSums, nScan);
    scan_final<<<nScan, 256, 0, stream>>>(cnt, blockSums, offsets, cursor, dinv, N);
    scatter_kernel<<<(E + 255) / 256, 256, 0, stream>>>(src, dst, cursor, srcAdj, E);

    // ---- prep: casts + weight packing ----
    cast_bf16<<<(n8 + 255) / 256, 256, 0, stream>>>(x, xb, n8);
    pack_w<<<8, 256, 0, stream>>>(W1, Wp1, FDIM, 8);
    pack_w<<<8, 256, 0, stream>>>(W2, Wp2, FDIM, 8);
    pack_w<<<3, 256, 0, stream>>>(Wc, Wpc, FCLS, 3);

    // ---- layer 1 ----
    gemm_mfma<<<mfmaBlocks, 256, 0, stream>>>(xb, Wp1, Hbuf, N);
    agg_fused<<<aggBlocks, 256, 0, stream>>>(Hbuf, dinv, b1, srcAdj, offsets, Abuf, N);

    // ---- layer 2 ----
    gemm_mfma<<<mfmaBlocks, 256, 0, stream>>>(Abuf, Wp2, Hbuf, N);
    agg_fused<<<aggBlocks, 256, 0, stream>>>(Hbuf, dinv, b2, srcAdj, offsets, Abuf, N);

    // ---- classifier ----
    classifier_mfma<<<mfmaBlocks, 256, 0, stream>>>(Abuf, Wpc, bc, out, N);
}

// Round 5
// 210.492 us; speedup vs baseline: 13.7132x; 1.0641x over previous
//
#include <hip/hip_runtime.h>

#define FDIM 128
#define FCLS 40
#define EPB  2048      // edges per binning block
#define BSH  10        // bucket shift: 1024 nodes per bucket

typedef short s16x8 __attribute__((ext_vector_type(8)));   // 8 bf16 (4 VGPRs)
typedef float f32x4 __attribute__((ext_vector_type(4)));   // MFMA accumulator

// ---- bf16 helpers (bit-level, RNE) ----------------------------------------
__device__ __forceinline__ float bf2f(unsigned short u) {
    union { unsigned int i; float f; } v; v.i = ((unsigned int)u) << 16; return v.f;
}
__device__ __forceinline__ unsigned short f2bf(float f) {
    union { float f; unsigned int i; } v; v.f = f;
    unsigned int u = v.i + 0x7FFFu + ((v.i >> 16) & 1u);   // round-nearest-even
    return (unsigned short)(u >> 16);
}

// ---------------------------------------------------------------------------
// CSR build, bucketed (no global atomics anywhere):
// 1) bin_hist:    per-block LDS histogram of dst>>BSH -> hist[bin][blk]
// 2) bucket_scan: exclusive scan of hist (1 block)
// 3) bin_scatter: (src,dst) pairs -> binned[], grouped by bucket
// 4) node_hist:   per-bucket LDS node counts -> cnt[] (coalesced)
// 5) node scan -> offsets[] (+dinv)
// 6) csr_scatter: per-bucket exact positions via LDS cursors -> srcAdj[]
// ---------------------------------------------------------------------------
__global__ __launch_bounds__(256) void bin_hist(const int* __restrict__ dst,
                                                int* __restrict__ hist,
                                                int E, int nblkA, int NB) {
    __shared__ int h[64];
    int t = threadIdx.x;
    if (t < 64) h[t] = 0;
    __syncthreads();
    int base = blockIdx.x * EPB;
    int end = min(base + EPB, E);
    for (int i = base + t; i < end; i += 256) atomicAdd(&h[dst[i] >> BSH], 1);
    __syncthreads();
    if (t < NB) hist[t * nblkA + blockIdx.x] = h[t];
}

// single-block exclusive scan, 4096 elems/iter (16/thread)
__global__ __launch_bounds__(256) void bucket_scan(int* __restrict__ data, int n) {
    __shared__ int s[256];
    __shared__ int carryS;
    int t = threadIdx.x;
    if (t == 0) carryS = 0;
    __syncthreads();
    for (int base = 0; base < n; base += 4096) {
        int v[16]; int sum = 0;
        int idx = base + t * 16;
#pragma unroll
        for (int j = 0; j < 16; ++j) { v[j] = (idx + j < n) ? data[idx + j] : 0; sum += v[j]; }
        s[t] = sum;
        __syncthreads();
        for (int off = 1; off < 256; off <<= 1) {
            int x = (t >= off) ? s[t - off] : 0;
            __syncthreads();
            s[t] += x;
            __syncthreads();
        }
        int run = carryS + s[t] - sum;
#pragma unroll
        for (int j = 0; j < 16; ++j) {
            if (idx + j < n) data[idx + j] = run;
            run += v[j];
        }
        int tot = s[255];
        __syncthreads();
        if (t == 0) carryS += tot;
        __syncthreads();
    }
}

__global__ __launch_bounds__(256) void bin_scatter(const int* __restrict__ src,
                                                   const int* __restrict__ dst,
                                                   const int* __restrict__ histS,
                                                   int2* __restrict__ binned,
                                                   int E, int nblkA, int NB) {
    __shared__ int cur[64];
    int t = threadIdx.x;
    if (t < NB) cur[t] = histS[t * nblkA + blockIdx.x];
    __syncthreads();
    int base = blockIdx.x * EPB;
    int end = min(base + EPB, E);
    for (int i = base + t; i < end; i += 256) {
        int d = dst[i];
        int pos = atomicAdd(&cur[d >> BSH], 1);     // LDS atomic
        binned[pos] = make_int2(src[i], d);
    }
}

__global__ __launch_bounds__(256) void node_hist(const int2* __restrict__ binned,
                                                 const int* __restrict__ histS,
                                                 int* __restrict__ cnt,
                                                 int N, int E, int nblkA, int NB) {
    int b = blockIdx.x;
    int node0 = b << BSH;
    int node1 = min(node0 + (1 << BSH), N);
    __shared__ int c[1 << BSH];
    int t = threadIdx.x;
    for (int i = t; i < (1 << BSH); i += 256) c[i] = 0;
    __syncthreads();
    int lo = histS[b * nblkA];
    int hi = (b == NB - 1) ? E : histS[(b + 1) * nblkA];
    for (int i = lo + t; i < hi; i += 256) {
        int2 p = binned[i];
        atomicAdd(&c[p.y - node0], 1);              // LDS atomic
    }
    __syncthreads();
    for (int i = t; i < node1 - node0; i += 256) cnt[node0 + i] = c[i];
}

__global__ __launch_bounds__(256) void scan_partial(const int* __restrict__ cnt,
                                                    int* __restrict__ blockSums, int N) {
    __shared__ int s[256];
    int t = threadIdx.x;
    int base = blockIdx.x * 1024 + t * 4;
    int v = 0;
#pragma unroll
    for (int j = 0; j < 4; ++j) if (base + j < N) v += cnt[base + j];
    s[t] = v;
    __syncthreads();
    for (int off = 128; off > 0; off >>= 1) {
        if (t < off) s[t] += s[t + off];
        __syncthreads();
    }
    if (t == 0) blockSums[blockIdx.x] = s[0];
}

__global__ __launch_bounds__(256) void scan_block(int* __restrict__ blockSums, int nb) {
    __shared__ int s[256];
    int t = threadIdx.x;
    s[t] = (t < nb) ? blockSums[t] : 0;
    __syncthreads();
    for (int off = 1; off < 256; off <<= 1) {
        int x = 0;
        if (t >= off) x = s[t - off];
        __syncthreads();
        s[t] += x;
        __syncthreads();
    }
    if (t < nb) blockSums[t] = (t > 0) ? s[t - 1] : 0;   // exclusive
}

__global__ __launch_bounds__(256) void scan_final(const int* __restrict__ cnt,
                                                  const int* __restrict__ blockSums,
                                                  int* __restrict__ offsets,
                                                  float* __restrict__ dinv, int N) {
    __shared__ int s[256];
    int t = threadIdx.x;
    int idx = blockIdx.x * 1024 + t * 4;
    int v[4];
    int sum = 0;
#pragma unroll
    for (int j = 0; j < 4; ++j) {
        v[j] = (idx + j < N) ? cnt[idx + j] : 0;
        sum += v[j];
    }
    s[t] = sum;
    __syncthreads();
    for (int off = 1; off < 256; off <<= 1) {
        int x = 0;
        if (t >= off) x = s[t - off];
        __syncthreads();
        s[t] += x;
        __syncthreads();
    }
    int running = blockSums[blockIdx.x] + s[t] - sum;    // exclusive prefix
#pragma unroll
    for (int j = 0; j < 4; ++j) {
        if (idx + j < N) {
            offsets[idx + j] = running;
            dinv[idx + j]    = rsqrtf((float)v[j] + 1.0f);
            running += v[j];
            if (idx + j == N - 1) offsets[N] = running;
        }
    }
}

__global__ __launch_bounds__(256) void csr_scatter(const int2* __restrict__ binned,
                                                   const int* __restrict__ offsets,
                                                   int* __restrict__ srcAdj, int N) {
    int b = blockIdx.x;
    int node0 = b << BSH;
    int node1 = min(node0 + (1 << BSH), N);
    __shared__ int cur[1 << BSH];
    int t = threadIdx.x;
    for (int i = t; i < node1 - node0; i += 256) cur[i] = offsets[node0 + i];
    __syncthreads();
    int lo = offsets[node0];
    int hi = offsets[node1];
    for (int i = lo + t; i < hi; i += 256) {
        int2 p = binned[i];
        int pos = atomicAdd(&cur[p.y - node0], 1);   // LDS atomic
        srcAdj[pos] = p.x;                           // write stays in bucket's L2 region
    }
}

// ---------------------------------------------------------------------------
// prep: pack W [128][ncols] f32 into MFMA B-fragment order, bf16.
// ---------------------------------------------------------------------------
__global__ __launch_bounds__(256) void pack_w(const float* __restrict__ W,
                                              unsigned short* __restrict__ Wp,
                                              int ncols, int nct) {
    int t = blockIdx.x * 256 + threadIdx.x;
    if (t >= nct * 256) return;
    int lane = t & 63, ks = (t >> 6) & 3, ct = t >> 8;
    int n  = ct * 16 + (lane & 15);
    int kb = ks * 32 + (lane >> 4) * 8;
    unsigned short v[8];
#pragma unroll
    for (int j = 0; j < 8; ++j) {
        v[j] = (n < ncols) ? f2bf(W[(size_t)(kb + j) * ncols + n]) : (unsigned short)0;
    }
    ushort4* o = (ushort4*)(Wp + (size_t)t * 8);
    o[0] = ushort4{v[0], v[1], v[2], v[3]};
    o[1] = ushort4{v[4], v[5], v[6], v[7]};
}

// ---------------------------------------------------------------------------
// C[M,128](bf16) = A[M,128](f32, converted in-register) @ W(packed bf16)
// ---------------------------------------------------------------------------
__global__ __launch_bounds__(256) void gemm_mfma_f32A(const float* __restrict__ A,
                                                      const unsigned short* __restrict__ Wp,
                                                      unsigned short* __restrict__ C, int M) {
    int wave = threadIdx.x >> 6;
    int lane = threadIdx.x & 63;
    int row0 = (blockIdx.x * 4 + wave) * 16;
    if (row0 >= M) return;
    int m = lane & 15;
    int g = lane >> 4;

    const float4* Arow = (const float4*)(A + (size_t)(row0 + m) * FDIM);
    s16x8 a[4];
#pragma unroll
    for (int ks = 0; ks < 4; ++ks) {
        float4 lo = Arow[ks * 8 + g * 2];
        float4 hi = Arow[ks * 8 + g * 2 + 1];
        s16x8 av;
        av[0] = (short)f2bf(lo.x); av[1] = (short)f2bf(lo.y);
        av[2] = (short)f2bf(lo.z); av[3] = (short)f2bf(lo.w);
        av[4] = (short)f2bf(hi.x); av[5] = (short)f2bf(hi.y);
        av[6] = (short)f2bf(hi.z); av[7] = (short)f2bf(hi.w);
        a[ks] = av;
    }

    for (int ct = 0; ct < 8; ++ct) {
        f32x4 acc = {0.f, 0.f, 0.f, 0.f};
#pragma unroll
        for (int ks = 0; ks < 4; ++ks) {
            s16x8 b = *(const s16x8*)(Wp + ((size_t)((ct * 4 + ks) * 64 + lane)) * 8);
            acc = __builtin_amdgcn_mfma_f32_16x16x32_bf16(a[ks], b, acc, 0, 0, 0);
        }
        int n  = ct * 16 + m;
        int r0 = row0 + g * 4;
#pragma unroll
        for (int r = 0; r < 4; ++r)
            C[(size_t)(r0 + r) * FDIM + n] = f2bf(acc[r]);
    }
}

// bf16-A variant (layer 2)
__global__ __launch_bounds__(256) void gemm_mfma(const unsigned short* __restrict__ A,
                                                 const unsigned short* __restrict__ Wp,
                                                 unsigned short* __restrict__ C, int M) {
    int wave = threadIdx.x >> 6;
    int lane = threadIdx.x & 63;
    int row0 = (blockIdx.x * 4 + wave) * 16;
    if (row0 >= M) return;
    int m = lane & 15;
    int g = lane >> 4;

    const s16x8* Arow = (const s16x8*)(A + (size_t)(row0 + m) * FDIM);
    s16x8 a[4];
#pragma unroll
    for (int ks = 0; ks < 4; ++ks) a[ks] = Arow[ks * 4 + g];

    for (int ct = 0; ct < 8; ++ct) {
        f32x4 acc = {0.f, 0.f, 0.f, 0.f};
#pragma unroll
        for (int ks = 0; ks < 4; ++ks) {
            s16x8 b = *(const s16x8*)(Wp + ((size_t)((ct * 4 + ks) * 64 + lane)) * 8);
            acc = __builtin_amdgcn_mfma_f32_16x16x32_bf16(a[ks], b, acc, 0, 0, 0);
        }
        int n  = ct * 16 + m;
        int r0 = row0 + g * 4;
#pragma unroll
        for (int r = 0; r < 4; ++r)
            C[(size_t)(r0 + r) * FDIM + n] = f2bf(acc[r]);
    }
}

// ---------------------------------------------------------------------------
// out[M,40](f32) = A[M,128](bf16) @ Wc(packed, zero-padded) + bc
// ---------------------------------------------------------------------------
__global__ __launch_bounds__(256) void classifier_mfma(const unsigned short* __restrict__ A,
                                                       const unsigned short* __restrict__ Wp,
                                                       const float* __restrict__ bc,
                                                       float* __restrict__ out, int M) {
    int wave = threadIdx.x >> 6;
    int lane = threadIdx.x & 63;
    int row0 = (blockIdx.x * 4 + wave) * 16;
    if (row0 >= M) return;
    int m = lane & 15;
    int g = lane >> 4;

    const s16x8* Arow = (const s16x8*)(A + (size_t)(row0 + m) * FDIM);
    s16x8 a[4];
#pragma unroll
    for (int ks = 0; ks < 4; ++ks) a[ks] = Arow[ks * 4 + g];

    for (int ct = 0; ct < 3; ++ct) {
        f32x4 acc = {0.f, 0.f, 0.f, 0.f};
#pragma unroll
        for (int ks = 0; ks < 4; ++ks) {
            s16x8 b = *(const s16x8*)(Wp + ((size_t)((ct * 4 + ks) * 64 + lane)) * 8);
            acc = __builtin_amdgcn_mfma_f32_16x16x32_bf16(a[ks], b, acc, 0, 0, 0);
        }
        int n = ct * 16 + m;
        if (n < FCLS) {
            float bias = bc[n];
            int r0 = row0 + g * 4;
#pragma unroll
            for (int r = 0; r < 4; ++r)
                out[(size_t)(r0 + r) * FCLS + n] = acc[r] + bias;
        }
    }
}

// ---------------------------------------------------------------------------
// Fused aggregation (bf16 gather -> bf16 out), f32 accumulation
// ---------------------------------------------------------------------------
__global__ __launch_bounds__(256) void agg_fused(const unsigned short* __restrict__ H,
                                                 const float* __restrict__ dinv,
                                                 const float* __restrict__ bias,
                                                 const int* __restrict__ srcAdj,
                                                 const int* __restrict__ offsets,
                                                 unsigned short* __restrict__ OUT, int N) {
    int node = blockIdx.x * 8 + (threadIdx.x >> 5);
    if (node >= N) return;
    int lane = threadIdx.x & 31;

    const ushort4* H4 = (const ushort4*)H;         // row stride = 32 ushort4
    float di = dinv[node];
    float d2 = di * di;

    ushort4 h = H4[(size_t)node * 32 + lane];
    float4 acc;
    acc.x = bf2f(h.x) * d2; acc.y = bf2f(h.y) * d2;
    acc.z = bf2f(h.z) * d2; acc.w = bf2f(h.w) * d2;

    int e   = offsets[node];
    int end = offsets[node + 1];
    for (; e + 4 <= end; e += 4) {
        int s0 = srcAdj[e + 0], s1 = srcAdj[e + 1];
        int s2 = srcAdj[e + 2], s3 = srcAdj[e + 3];
        float c0 = dinv[s0] * di, c1 = dinv[s1] * di;
        float c2 = dinv[s2] * di, c3 = dinv[s3] * di;
        ushort4 a0 = H4[(size_t)s0 * 32 + lane];
        ushort4 a1 = H4[(size_t)s1 * 32 + lane];
        ushort4 a2 = H4[(size_t)s2 * 32 + lane];
        ushort4 a3 = H4[(size_t)s3 * 32 + lane];
        acc.x = fmaf(bf2f(a0.x), c0, acc.x); acc.y = fmaf(bf2f(a0.y), c0, acc.y);
        acc.z = fmaf(bf2f(a0.z), c0, acc.z); acc.w = fmaf(bf2f(a0.w), c0, acc.w);
        acc.x = fmaf(bf2f(a1.x), c1, acc.x); acc.y = fmaf(bf2f(a1.y), c1, acc.y);
        acc.z = fmaf(bf2f(a1.z), c1, acc.z); acc.w = fmaf(bf2f(a1.w), c1, acc.w);
        acc.x = fmaf(bf2f(a2.x), c2, acc.x); acc.y = fmaf(bf2f(a2.y), c2, acc.y);
        acc.z = fmaf(bf2f(a2.z), c2, acc.z); acc.w = fmaf(bf2f(a2.w), c2, acc.w);
        acc.x = fmaf(bf2f(a3.x), c3, acc.x); acc.y = fmaf(bf2f(a3.y), c3, acc.y);
        acc.z = fmaf(bf2f(a3.z), c3, acc.z); acc.w = fmaf(bf2f(a3.w), c3, acc.w);
    }
    for (; e < end; ++e) {
        int s0 = srcAdj[e];
        float c0 = dinv[s0] * di;
        ushort4 a0 = H4[(size_t)s0 * 32 + lane];
        acc.x = fmaf(bf2f(a0.x), c0, acc.x); acc.y = fmaf(bf2f(a0.y), c0, acc.y);
        acc.z = fmaf(bf2f(a0.z), c0, acc.z); acc.w = fmaf(bf2f(a0.w), c0, acc.w);
    }

    float4 bb = ((const float4*)bias)[lane];
    acc.x = fmaxf(acc.x + bb.x, 0.0f);
    acc.y = fmaxf(acc.y + bb.y, 0.0f);
    acc.z = fmaxf(acc.z + bb.z, 0.0f);
    acc.w = fmaxf(acc.w + bb.w, 0.0f);
    ((ushort4*)OUT)[(size_t)node * 32 + lane] =
        ushort4{f2bf(acc.x), f2bf(acc.y), f2bf(acc.z), f2bf(acc.w)};
}

// ---------------------------------------------------------------------------
extern "C" void kernel_launch(void* const* d_in, const int* in_sizes, int n_in,
                              void* d_out, int out_size, void* d_ws, size_t ws_size,
                              hipStream_t stream) {
    const float* x  = (const float*)d_in[0];
    const int*   ei = (const int*)d_in[1];
    const float* W1 = (const float*)d_in[2];
    const float* b1 = (const float*)d_in[3];
    const float* W2 = (const float*)d_in[4];
    const float* b2 = (const float*)d_in[5];
    const float* Wc = (const float*)d_in[6];
    const float* bc = (const float*)d_in[7];
    float* out = (float*)d_out;

    int N = in_sizes[0] / FDIM;
    int E = in_sizes[1] / 2;
    const int* src = ei;
    const int* dst = ei + E;

    int nblkA = (E + EPB - 1) / EPB;            // 391
    int NB    = (N + (1 << BSH) - 1) >> BSH;    // 49
    int nScan = (N + 1023) / 1024;              // 49
    int mfmaBlocks = (N / 16 + 3) / 4;          // 782
    int aggBlocks  = (N + 7) / 8;

    // workspace layout:
    // binned[E int2] | srcAdj[E] | cnt[N] | offsets[N+1] | hist[NB*nblkA]
    // | blockSums[256] | dinv[N] | Wp1 | Wp2 | Wpc | Hbuf bf16 | Abuf bf16
    int2* binned   = (int2*)d_ws;
    int*  srcAdj   = (int*)(binned + E);
    int*  cnt      = srcAdj + E;
    int*  offsets  = cnt + N;
    int*  hist     = offsets + (N + 1);
    int*  blockSums = hist + NB * nblkA;
    float* dinv    = (float*)(blockSums + 256);
    unsigned short* Wp1 = (unsigned short*)(dinv + N);
    unsigned short* Wp2 = Wp1 + 8 * 4 * 64 * 8;
    unsigned short* Wpc = Wp2 + 8 * 4 * 64 * 8;
    unsigned short* Hbuf = Wpc + 3 * 4 * 64 * 8;
    unsigned short* Abuf = Hbuf + (size_t)N * FDIM;

    // ---- CSR build (no global atomics) ----
    bin_hist<<<nblkA, 256, 0, stream>>>(dst, hist, E, nblkA, NB);
    bucket_scan<<<1, 256, 0, stream>>>(hist, NB * nblkA);
    bin_scatter<<<nblkA, 256, 0, stream>>>(src, dst, hist, binned, E, nblkA, NB);
    node_hist<<<NB, 256, 0, stream>>>(binned, hist, cnt, N, E, nblkA, NB);
    scan_partial<<<nScan, 256, 0, stream>>>(cnt, blockSums, N);
    scan_block<<<1, 256, 0, stream>>>(blockSums, nScan);
    scan_final<<<nScan, 256, 0, stream>>>(cnt, blockSums, offsets, dinv, N);
    csr_scatter<<<NB, 256, 0, stream>>>(binned, offsets, srcAdj, N);

    // ---- weight packing ----
    pack_w<<<8, 256, 0, stream>>>(W1, Wp1, FDIM, 8);
    pack_w<<<8, 256, 0, stream>>>(W2, Wp2, FDIM, 8);
    pack_w<<<3, 256, 0, stream>>>(Wc, Wpc, FCLS, 3);

    // ---- layer 1 (x read as f32, converted in-register) ----
    gemm_mfma_f32A<<<mfmaBlocks, 256, 0, stream>>>(x, Wp1, Hbuf, N);
    agg_fused<<<aggBlocks, 256, 0, stream>>>(Hbuf, dinv, b1, srcAdj, offsets, Abuf, N);

    // ---- layer 2 ----
    gemm_mfma<<<mfmaBlocks, 256, 0, stream>>>(Abuf, Wp2, Hbuf, N);
    agg_fused<<<aggBlocks, 256, 0, stream>>>(Hbuf, dinv, b2, srcAdj, offsets, Abuf, N);

    // ---- classifier ----
    classifier_mfma<<<mfmaBlocks, 256, 0, stream>>>(Abuf, Wpc, bc, out, N);
}